// Round 5
// baseline (1322.591 us; speedup 1.0000x reference)
//
#include <hip/hip_runtime.h>

typedef __attribute__((ext_vector_type(8))) short bf16x8;
typedef __attribute__((ext_vector_type(4))) float f32x4;
typedef __attribute__((ext_vector_type(16))) float f32x16;
typedef unsigned short ushort_t;
typedef unsigned int uint32;

static constexpr int Bsz = 8;       // batch
static constexpr int T   = 8192;    // sequence length
static constexpr int Dd  = 128;     // head dim
static constexpr int NB  = 8;       // chunks
static constexpr int N   = T / NB;  // 1024 tokens per chunk
static constexpr int Nk  = 64;      // keys per tile
static constexpr int TPC = N / Nk;  // 16 tiles per chunk

__device__ __forceinline__ float bf2f(ushort_t u){
  return __uint_as_float(((uint32)u) << 16);
}
__device__ __forceinline__ ushort_t f2bf(float f){
  uint32 u = __float_as_uint(f);
  u += 0x7FFFu + ((u >> 16) & 1u);   // RNE
  return (ushort_t)(u >> 16);
}
__device__ __forceinline__ uint32 pk2(float a, float b){
  return (uint32)f2bf(a) | ((uint32)f2bf(b) << 16);
}

// ---------------------------------------------------------------------------
// Projection: grid (nt/64, 3).  y=0: Qb=(XWq+bq)*scale*log2e row-major bf16
//                               y=1: Kb=(XWk+bk) row-major bf16
//                               y=2: VbT=(XWv+bv) TRANSPOSED [b][d][t] bf16
// ---------------------------------------------------------------------------
__global__ __launch_bounds__(256)
void proj_kernel(const float* __restrict__ X,
                 const float* __restrict__ Wq, const float* __restrict__ bq,
                 const float* __restrict__ Wk, const float* __restrict__ bk,
                 const float* __restrict__ Wv, const float* __restrict__ bv,
                 ushort_t* __restrict__ Qb, ushort_t* __restrict__ Kb,
                 ushort_t* __restrict__ VbT, float scale)
{
  __shared__ __align__(16) char smem[49152];
  short* Xt = (short*)smem;             // 16KB [64][128] swz
  short* Wt = (short*)(smem + 16384);   // 32KB [col][k] swz
  float* Brot = (float*)smem;           // 32KB overlay (V bounce)

  const int which = blockIdx.y;
  const float* W   = (which == 0) ? Wq : (which == 1) ? Wk : Wv;
  const float* bia = (which == 0) ? bq : (which == 1) ? bk : bv;
  const float sc   = (which == 0) ? scale : 1.0f;

  const int tid  = threadIdx.x;
  const int wave = tid >> 6;
  const int lane = tid & 63;
  const int lg   = lane >> 4;
  const int lr   = lane & 15;
  const int row0 = blockIdx.x * 64;

  for (int c = tid; c < Dd*32; c += 256){
    int k  = c >> 5;
    int j0 = (c & 31) * 4;
    const float4 w = *reinterpret_cast<const float4*>(W + (size_t)k*Dd + j0);
    const float* wf = reinterpret_cast<const float*>(&w);
    #pragma unroll
    for (int e = 0; e < 4; e++){
      int jj = j0 + e;
      int inner = (k & 7) | (((k >> 3) ^ (jj & 7)) << 3);
      Wt[jj*Dd + inner] = (short)f2bf(wf[e]);
    }
  }
  for (int c = tid; c < 64*32; c += 256){
    int r  = c >> 5;
    int k0 = (c & 31) * 4;
    const float4 xv = *reinterpret_cast<const float4*>(X + (size_t)(row0 + r)*Dd + k0);
    const float* xf = reinterpret_cast<const float*>(&xv);
    int swz  = (k0 >> 3) ^ (r & 7);
    int base = r*Dd + swz*8 + (k0 & 7);
    #pragma unroll
    for (int e = 0; e < 4; e++) Xt[base + e] = (short)f2bf(xf[e]);
  }
  __syncthreads();

  f32x4 acc[8];
  #pragma unroll
  for (int nf = 0; nf < 8; nf++) acc[nf] = (f32x4){0.f,0.f,0.f,0.f};

  #pragma unroll
  for (int kk = 0; kk < 4; kk++){
    int arow = wave*16 + lr;
    int swz  = (lg + kk*4) ^ (lr & 7);
    bf16x8 a = *reinterpret_cast<const bf16x8*>(&Xt[arow*Dd + swz*8]);
    #pragma unroll
    for (int nf = 0; nf < 8; nf++){
      int col  = nf*16 + lr;
      bf16x8 b = *reinterpret_cast<const bf16x8*>(&Wt[col*Dd + swz*8]);
      acc[nf] = __builtin_amdgcn_mfma_f32_16x16x32_bf16(a, b, acc[nf], 0, 0, 0);
    }
  }

  if (which < 2){
    ushort_t* out = (which == 0) ? Qb : Kb;
    #pragma unroll
    for (int nf = 0; nf < 8; nf++){
      int col = nf*16 + lr;
      float bv_ = bia[col];
      #pragma unroll
      for (int r = 0; r < 4; r++){
        int grow = row0 + wave*16 + lg*4 + r;
        out[(size_t)grow*Dd + col] = f2bf((acc[nf][r] + bv_) * sc);
      }
    }
  } else {
    __syncthreads();
    #pragma unroll
    for (int nf = 0; nf < 8; nf++){
      int col = nf*16 + lr;
      float bv_ = bia[col];
      #pragma unroll
      for (int r = 0; r < 4; r++){
        int row_l = wave*16 + lg*4 + r;
        Brot[row_l*Dd + ((col + row_l) & 127)] = acc[nf][r] + bv_;
      }
    }
    __syncthreads();
    const int bb  = row0 >> 13;
    const int tq0 = row0 & (T - 1);
    const size_t vb = (size_t)bb * Dd * T;
    #pragma unroll 4
    for (int dd = 0; dd < 32; ++dd){
      int d = wave*32 + dd;
      float v = Brot[lane*Dd + ((d + lane) & 127)];
      VbT[vb + (size_t)d*T + tq0 + lane] = f2bf(v);
    }
  }
}

// ---------------------------------------------------------------------------
// Unified per-iteration attention step. 256 threads = 4 waves; each wave owns
// a 32-row query strip (wg M-tile = 128). Swapped QK^T via 32x32x16 MFMA:
// lane owns one q-row (col = lane&31) in the SCORE domain; the PV accumulator
// is TRANSPOSED (lane = d column, q lives in the register index crow(r,h) =
// (r&3)+8*(r>>2)+4*h). Therefore the online O-rescale must use the factor of
// row crow(r,h) (shuffled from lane crow(r,h)), NOT the lane's own factor.
// The running max is EXACT (ratio=new_d/d_old is not representative-
// invariant): rescale skipped only when no row's max grew.
// ---------------------------------------------------------------------------
__global__ __launch_bounds__(256)
void attn_step(const ushort_t* __restrict__ Qb, const ushort_t* __restrict__ Kb,
               const ushort_t* __restrict__ VbT,
               const ushort_t* __restrict__ VcTr_hi, const ushort_t* __restrict__ VcTr_lo,
               ushort_t* __restrict__ VcTw_hi, ushort_t* __restrict__ VcTw_lo,
               float* __restrict__ VcF, float* __restrict__ m_st, float* __restrict__ d_st,
               float* __restrict__ Pacc, float* __restrict__ Pm, float* __restrict__ Pd,
               int iblk)
{
  __shared__ __align__(16) char smem[65536];
  short* Kt = (short*)smem;             // 16KB [64][128] swz
  short* Vt = (short*)(smem + 16384);   // 16KB [128][64] swz
  float* Brot = (float*)smem;           // 64KB overlay: per-wave 16KB bounce

  const int tid  = threadIdx.x;
  const int wave = tid >> 6;
  const int lane = tid & 63;
  const int l31  = lane & 31;
  const int h    = lane >> 5;

  // XCD-aware bijective swizzle (gridDim.x is always a multiple of 8)
  const int nwg = gridDim.x;
  const int bi  = (blockIdx.x & 7) * (nwg >> 3) + (blockIdx.x >> 3);

  const int g0 = Bsz * 8 * (iblk + 1);
  const bool is0 = (bi < g0);

  int b, qt, qrow0, t0, j;
  bool haslo;
  const ushort_t *qsrc, *ksrc, *vhi;

  if (is0){
    j = bi >> 6;
    int rem = bi & 63;
    b = rem >> 3; qt = rem & 7;
    qrow0 = b*T + iblk*N + qt*128;
    t0 = j*N;
    haslo = (j < iblk);
    qsrc = Qb; ksrc = Kb;
    vhi = haslo ? VcTr_hi : VbT;
  } else {
    int bi2 = bi - g0;
    int per = 8 * iblk;
    b = bi2 / per;
    int rem = bi2 - b*per;
    j = rem >> 3; qt = rem & 7;      // j = jold
    qrow0 = b*T + j*N + qt*128;
    t0 = iblk*N;
    haslo = false;
    qsrc = Kb; ksrc = Qb;
    vhi = VbT;
  }
  const int krow0base = b*T + t0;
  const size_t vbase = (size_t)b * Dd * T;
  const ushort_t* vhiB = vhi + vbase;
  const ushort_t* vloB = VcTr_lo + vbase;

  // Q fragments (B-operand): lane's q-row = qrow0 + wave*32 + l31,
  // k = ks*16 + h*8 + e  -> contiguous bf16x8 loads.
  bf16x8 qf[8];
  {
    const ushort_t* qp = qsrc + (size_t)(qrow0 + wave*32 + l31)*Dd + h*8;
    #pragma unroll
    for (int ks = 0; ks < 8; ++ks) qf[ks] = *reinterpret_cast<const bf16x8*>(qp + ks*16);
  }

  f32x16 o[4];
  #pragma unroll
  for (int db = 0; db < 4; ++db) o[db] = (f32x16)(0.0f);
  float m_run = -INFINITY;
  float d_run = 0.f;

  for (int kt = 0; kt < TPC; ++kt){
    const int krow0 = krow0base + kt*Nk;
    const int tt0   = t0 + kt*Nk;

    __syncthreads();
    #pragma unroll
    for (int it = 0; it < 4; ++it){
      int c = tid + it*256;
      int r = c >> 4, kb = c & 15;
      bf16x8 v = *reinterpret_cast<const bf16x8*>(ksrc + (size_t)(krow0 + r)*Dd + kb*8);
      *reinterpret_cast<bf16x8*>(&Kt[r*Dd + ((kb ^ (r & 7)))*8]) = v;
    }
    #pragma unroll
    for (int it = 0; it < 4; ++it){
      int c = tid + it*256;
      int d = c >> 3, sg = c & 7;
      bf16x8 v = *reinterpret_cast<const bf16x8*>(vhiB + (size_t)d*T + tt0 + sg*8);
      *reinterpret_cast<bf16x8*>(&Vt[d*Nk + ((sg ^ (d & 7)))*8]) = v;
    }
    __syncthreads();

    // S^T = K · Q^T : C[kv][q], q = lane&31
    f32x16 c0 = (f32x16)(0.0f), c1 = (f32x16)(0.0f);
    #pragma unroll
    for (int ks = 0; ks < 8; ++ks){
      int swz = (2*ks + h) ^ (l31 & 7);
      bf16x8 ka = *reinterpret_cast<const bf16x8*>(&Kt[l31*Dd + swz*8]);
      bf16x8 kb = *reinterpret_cast<const bf16x8*>(&Kt[(32 + l31)*Dd + swz*8]);
      c0 = __builtin_amdgcn_mfma_f32_32x32x16_bf16(ka, qf[ks], c0, 0, 0, 0);
      c1 = __builtin_amdgcn_mfma_f32_32x32x16_bf16(kb, qf[ks], c1, 0, 0, 0);
    }

    // per-lane tile max over own 32 values, then sync across halves
    float tm = c0[0];
    #pragma unroll
    for (int r = 1; r < 16; ++r) tm = fmaxf(tm, c0[r]);
    #pragma unroll
    for (int r = 0; r < 16; ++r) tm = fmaxf(tm, c1[r]);
    tm = fmaxf(tm, __shfl_xor(tm, 32));

    // EXACT skip: only when no row's max grew (then scl==1 for all rows).
    // NOTE: o is q-transposed (q = crow(r,h), lane = d) -> each register row
    // needs ITS row's factor, shuffled from lane crow(r,h).
    if (!__all(tm <= m_run)){
      float mn  = fmaxf(m_run, tm);
      float scl = exp2f(m_run - mn);   // factor for q-row l31 (this lane)
      d_run *= scl;
      m_run = mn;
      #pragma unroll
      for (int r = 0; r < 16; ++r){
        int rr = (r & 3) + 8*(r >> 2) + 4*h;
        float sr = __shfl(scl, rr);
        o[0][r] *= sr; o[1][r] *= sr; o[2][r] *= sr; o[3][r] *= sr;
      }
    }

    // p = exp2(s - m_run), in place; row-sum (per-lane row q=l31)
    float ps = 0.f;
    #pragma unroll
    for (int r = 0; r < 16; ++r){ c0[r] = exp2f(c0[r] - m_run); ps += c0[r]; }
    #pragma unroll
    for (int r = 0; r < 16; ++r){ c1[r] = exp2f(c1[r] - m_run); ps += c1[r]; }
    ps += __shfl_xor(ps, 32);
    d_run += ps;

    // pack P to bf16 words and exchange halves
    uint32 w[16], wp[16];
    #pragma unroll
    for (int q = 0; q < 8; ++q){
      w[q]     = pk2(c0[2*q], c0[2*q+1]);
      w[8 + q] = pk2(c1[2*q], c1[2*q+1]);
    }
    #pragma unroll
    for (int q = 0; q < 16; ++q) wp[q] = (uint32)__shfl_xor((int)w[q], 32);

    // O += P @ V(hi)
    #pragma unroll
    for (int s = 0; s < 4; ++s){
      union { uint32 u[4]; bf16x8 v; } af;
      af.u[0] = h ? wp[4*s+2] : w[4*s];
      af.u[1] = h ? wp[4*s+3] : w[4*s+1];
      af.u[2] = h ? w[4*s+2]  : wp[4*s];
      af.u[3] = h ? w[4*s+3]  : wp[4*s+1];
      #pragma unroll
      for (int db = 0; db < 4; ++db){
        int swz = (2*s + h) ^ (l31 & 7);
        bf16x8 bv = *reinterpret_cast<const bf16x8*>(&Vt[(db*32 + l31)*Nk + swz*8]);
        o[db] = __builtin_amdgcn_mfma_f32_32x32x16_bf16(af.v, bv, o[db], 0, 0, 0);
      }
    }
    if (haslo){
      __syncthreads();
      #pragma unroll
      for (int it = 0; it < 4; ++it){
        int c = tid + it*256;
        int d = c >> 3, sg = c & 7;
        bf16x8 v = *reinterpret_cast<const bf16x8*>(vloB + (size_t)d*T + tt0 + sg*8);
        *reinterpret_cast<bf16x8*>(&Vt[d*Nk + ((sg ^ (d & 7)))*8]) = v;
      }
      __syncthreads();
      #pragma unroll
      for (int s = 0; s < 4; ++s){
        union { uint32 u[4]; bf16x8 v; } af;
        af.u[0] = h ? wp[4*s+2] : w[4*s];
        af.u[1] = h ? wp[4*s+3] : w[4*s+1];
        af.u[2] = h ? w[4*s+2]  : wp[4*s];
        af.u[3] = h ? w[4*s+3]  : wp[4*s+1];
        #pragma unroll
        for (int db = 0; db < 4; ++db){
          int swz = (2*s + h) ^ (l31 & 7);
          bf16x8 bv = *reinterpret_cast<const bf16x8*>(&Vt[(db*32 + l31)*Nk + swz*8]);
          o[db] = __builtin_amdgcn_mfma_f32_32x32x16_bf16(af.v, bv, o[db], 0, 0, 0);
        }
      }
    }
  }

  if (is0){
    // split-KV partial write: D rows = q (reg-mapped), cols = d
    const int prow_base = b*1024 + qt*128 + wave*32;
    float* pa = Pacc + (size_t)j*8192*Dd;
    #pragma unroll
    for (int r = 0; r < 16; ++r){
      int qloc = (r & 3) + 8*(r >> 2) + 4*h;
      float* row = pa + (size_t)(prow_base + qloc)*Dd + l31;
      #pragma unroll
      for (int db = 0; db < 4; ++db) row[db*32] = o[db][r];
    }
    if (lane < 32){
      Pm[j*8192 + prow_base + l31] = m_run;
      Pd[j*8192 + prow_base + l31] = d_run;
    }
  } else {
    // faithful _update_state merge, in place on VcF (log2-domain m/d)
    const int growo = qrow0 + wave*32 + l31;
    float mo_o = m_st[growo], do_o = d_st[growo];
    float mn_o = fmaxf(mo_o, m_run);
    float nd_o = do_o * exp2f(mo_o - mn_o) + d_run * exp2f(m_run - mn_o);

    #pragma unroll
    for (int r = 0; r < 16; ++r){
      int rr = (r & 3) + 8*(r >> 2) + 4*h;
      float m_r  = __shfl(m_run, rr);
      float d_r  = __shfl(d_run, rr);
      float mo   = __shfl(mo_o, rr);
      float dold = __shfl(do_o, rr);
      float mn = fmaxf(mo, m_r);
      float se = exp2f(m_r - mn);
      float nd = dold * exp2f(mo - mn) + d_r * se;
      float ratio = nd / dold;
      float accm  = se / nd;
      size_t base = (size_t)(qrow0 + wave*32 + rr)*Dd + l31;
      #pragma unroll
      for (int db = 0; db < 4; ++db){
        float v = ratio * VcF[base + db*32] + o[db][r] * accm;
        VcF[base + db*32] = v;
        o[db][r] = v;
      }
    }
    if (lane < 32){ m_st[growo] = mn_o; d_st[growo] = nd_o; }

    // bounce-transpose updated rows into VcT(write) hi/lo
    __syncthreads();   // all waves done with Kt/Vt
    float* brot = Brot + wave*32*Dd;
    #pragma unroll
    for (int r = 0; r < 16; ++r){
      int rr = (r & 3) + 8*(r >> 2) + 4*h;
      #pragma unroll
      for (int db = 0; db < 4; ++db){
        int d = db*32 + l31;
        brot[rr*Dd + ((d + rr) & 127)] = o[db][r];
      }
    }
    __syncthreads();
    const int tabs = (qrow0 - b*T) + wave*32 + l31;
    #pragma unroll 4
    for (int dd = 0; dd < 64; ++dd){
      int d = dd*2 + h;
      float v = brot[l31*Dd + ((d + l31) & 127)];
      ushort_t hi = f2bf(v);
      VcTw_hi[vbase + (size_t)d*T + tabs] = hi;
      VcTw_lo[vbase + (size_t)d*T + tabs] = f2bf(v - bf2f(hi));
    }
  }
}

// ---------------------------------------------------------------------------
// Merge split-KV partials -> block iblk rows of VcF, m_st, d_st, VcT(write).
// grid = 128 (b, qt64), 256 threads. log2-domain m/d.
// ---------------------------------------------------------------------------
__global__ __launch_bounds__(256)
void merge_kernel(const float* __restrict__ Pacc, const float* __restrict__ Pm,
                  const float* __restrict__ Pd,
                  float* __restrict__ VcF, float* __restrict__ m_st, float* __restrict__ d_st,
                  ushort_t* __restrict__ VcTw_hi, ushort_t* __restrict__ VcTw_lo,
                  int iblk)
{
  __shared__ float Brot[64*Dd];   // 32KB rotation layout
  const int bi = blockIdx.x;
  const int b = bi >> 4, qt = bi & 15;
  const int tid = threadIdx.x;
  const int lrow = tid >> 2, dq = tid & 3;
  const int prow = b*1024 + qt*64 + lrow;
  const int grow = b*T + iblk*N + qt*64 + lrow;

  float M = -INFINITY;
  for (int jj = 0; jj <= iblk; ++jj) M = fmaxf(M, Pm[jj*8192 + prow]);

  float out[32];
  #pragma unroll
  for (int e = 0; e < 32; ++e) out[e] = 0.f;
  float D = 0.f;
  for (int jj = 0; jj <= iblk; ++jj){
    float wj = exp2f(Pm[jj*8192 + prow] - M);
    D += Pd[jj*8192 + prow] * wj;
    const float* pa = Pacc + ((size_t)jj*8192 + prow)*Dd + dq*32;
    #pragma unroll
    for (int e8 = 0; e8 < 8; ++e8){
      float4 v = *reinterpret_cast<const float4*>(pa + e8*4);
      out[e8*4+0] += v.x * wj;
      out[e8*4+1] += v.y * wj;
      out[e8*4+2] += v.z * wj;
      out[e8*4+3] += v.w * wj;
    }
  }
  float dinv = 1.f / D;
  #pragma unroll
  for (int e = 0; e < 32; ++e){
    int d = dq*32 + e;
    float v = out[e] * dinv;
    VcF[(size_t)grow*Dd + d] = v;
    Brot[lrow*Dd + ((d + lrow) & 127)] = v;
  }
  if (dq == 0){ m_st[grow] = M; d_st[grow] = D; }
  __syncthreads();

  const int wave = tid >> 6, lane = tid & 63;
  const int tq0 = iblk*N + qt*64;
  const size_t vb = (size_t)b * Dd * T;
  #pragma unroll 4
  for (int dd = 0; dd < 32; ++dd){
    int d = wave*32 + dd;
    float v = Brot[lane*Dd + ((d + lane) & 127)];
    ushort_t hi = f2bf(v);
    VcTw_hi[vb + (size_t)d*T + tq0 + lane] = hi;
    VcTw_lo[vb + (size_t)d*T + tq0 + lane] = f2bf(v - bf2f(hi));
  }
}

// ---------------------------------------------------------------------------
extern "C" void kernel_launch(void* const* d_in, const int* in_sizes, int n_in,
                              void* d_out, int out_size, void* d_ws, size_t ws_size,
                              hipStream_t stream)
{
  (void)in_sizes; (void)n_in; (void)out_size; (void)ws_size;

  const float* x  = (const float*)d_in[0];
  const float* Wq = (const float*)d_in[1];
  const float* bq = (const float*)d_in[2];
  const float* Wk = (const float*)d_in[3];
  const float* bk = (const float*)d_in[4];
  const float* Wv = (const float*)d_in[5];
  const float* bv = (const float*)d_in[6];

  float* VcF = (float*)d_out;          // fp32 master v_cache == output

  const size_t nt = (size_t)Bsz * T;   // 65536 rows
  char* p = (char*)d_ws;
  auto alloc = [&](size_t bytes) -> void* {
    void* r = (void*)p;
    p += (bytes + 255) & ~(size_t)255;
    return r;
  };
  ushort_t* Qb   = (ushort_t*)alloc(nt * Dd * 2);          // 16MB
  ushort_t* Kb   = (ushort_t*)alloc(nt * Dd * 2);          // 16MB
  ushort_t* VbT  = (ushort_t*)alloc(nt * Dd * 2);          // 16MB transposed raw V
  ushort_t* VcT[2][2];
  for (int c = 0; c < 2; ++c)
    for (int hh = 0; hh < 2; ++hh)
      VcT[c][hh] = (ushort_t*)alloc(nt * Dd * 2);          // 4 x 16MB
  float* m_st = (float*)alloc(nt * 4);
  float* d_st = (float*)alloc(nt * 4);
  float* Pacc = (float*)alloc((size_t)NB * 8192 * Dd * 4); // 33.5MB
  float* Pm   = (float*)alloc((size_t)NB * 8192 * 4);
  float* Pd   = (float*)alloc((size_t)NB * 8192 * 4);

  // 1/sqrt(128) * log2(e): scores computed directly in log2 domain
  const float scale = 0.08838834764831845f * 1.4426950408889634f;
  dim3 blk(256);

  proj_kernel<<<dim3((unsigned)(nt / 64), 3), blk, 0, stream>>>(
      x, Wq, bq, Wk, bk, Wv, bv, Qb, Kb, VbT, scale);

  for (int i = 0; i < NB; ++i){
    const int wb = i & 1, rb = wb ^ 1;
    const int grid = 64 * (2*i + 1);
    attn_step<<<grid, blk, 0, stream>>>(
        Qb, Kb, VbT,
        VcT[rb][0], VcT[rb][1], VcT[wb][0], VcT[wb][1],
        VcF, m_st, d_st, Pacc, Pm, Pd, i);
    merge_kernel<<<128, blk, 0, stream>>>(
        Pacc, Pm, Pd, VcF, m_st, d_st, VcT[wb][0], VcT[wb][1], i);
  }
}

// Round 6
// 1153.867 us; speedup vs baseline: 1.1462x; 1.1462x over previous
//
#include <hip/hip_runtime.h>

typedef __attribute__((ext_vector_type(8))) short bf16x8;
typedef __attribute__((ext_vector_type(4))) float f32x4;
typedef __attribute__((ext_vector_type(16))) float f32x16;
typedef unsigned short ushort_t;
typedef unsigned int uint32;

static constexpr int Bsz = 8;       // batch
static constexpr int T   = 8192;    // sequence length
static constexpr int Dd  = 128;     // head dim
static constexpr int NB  = 8;       // chunks
static constexpr int N   = T / NB;  // 1024 tokens per chunk
static constexpr int Nk  = 64;      // keys per tile
static constexpr int TPC = N / Nk;  // 16 tiles per chunk

__device__ __forceinline__ float bf2f(ushort_t u){
  return __uint_as_float(((uint32)u) << 16);
}
__device__ __forceinline__ ushort_t f2bf(float f){
  uint32 u = __float_as_uint(f);
  u += 0x7FFFu + ((u >> 16) & 1u);   // RNE
  return (ushort_t)(u >> 16);
}
// HW packed f32->bf16 (RNE): dst.lo16 = bf16(a), dst.hi16 = bf16(b)
__device__ __forceinline__ uint32 cvtpk(float a, float b){
  uint32 r;
  asm("v_cvt_pk_bf16_f32 %0, %1, %2" : "=v"(r) : "v"(a), "v"(b));
  return r;
}
__device__ __forceinline__ float exp2v(float x){
  float r;
  asm("v_exp_f32 %0, %1" : "=v"(r) : "v"(x));
  return r;
}
typedef __attribute__((address_space(1))) const unsigned int guint;
typedef __attribute__((address_space(3))) unsigned int luint;
__device__ __forceinline__ void gl16(const void* g, void* l){
  __builtin_amdgcn_global_load_lds((guint*)g, (luint*)l, 16, 0, 0);
}

// ---------------------------------------------------------------------------
// Projection: grid (nt/64, 3).  y=0: Qb=(XWq+bq)*scale*log2e row-major bf16
//                               y=1: Kb=(XWk+bk) row-major bf16
//                               y=2: VbT=(XWv+bv) TRANSPOSED [b][d][t] bf16
// ---------------------------------------------------------------------------
__global__ __launch_bounds__(256)
void proj_kernel(const float* __restrict__ X,
                 const float* __restrict__ Wq, const float* __restrict__ bq,
                 const float* __restrict__ Wk, const float* __restrict__ bk,
                 const float* __restrict__ Wv, const float* __restrict__ bv,
                 ushort_t* __restrict__ Qb, ushort_t* __restrict__ Kb,
                 ushort_t* __restrict__ VbT, float scale)
{
  __shared__ __align__(16) char smem[49152];
  short* Xt = (short*)smem;             // 16KB [64][128] swz
  short* Wt = (short*)(smem + 16384);   // 32KB [col][k] swz
  float* Brot = (float*)smem;           // 32KB overlay (V bounce)

  const int which = blockIdx.y;
  const float* W   = (which == 0) ? Wq : (which == 1) ? Wk : Wv;
  const float* bia = (which == 0) ? bq : (which == 1) ? bk : bv;
  const float sc   = (which == 0) ? scale : 1.0f;

  const int tid  = threadIdx.x;
  const int wave = tid >> 6;
  const int lane = tid & 63;
  const int lg   = lane >> 4;
  const int lr   = lane & 15;
  const int row0 = blockIdx.x * 64;

  for (int c = tid; c < Dd*32; c += 256){
    int k  = c >> 5;
    int j0 = (c & 31) * 4;
    const float4 w = *reinterpret_cast<const float4*>(W + (size_t)k*Dd + j0);
    const float* wf = reinterpret_cast<const float*>(&w);
    #pragma unroll
    for (int e = 0; e < 4; e++){
      int jj = j0 + e;
      int inner = (k & 7) | (((k >> 3) ^ (jj & 7)) << 3);
      Wt[jj*Dd + inner] = (short)f2bf(wf[e]);
    }
  }
  for (int c = tid; c < 64*32; c += 256){
    int r  = c >> 5;
    int k0 = (c & 31) * 4;
    const float4 xv = *reinterpret_cast<const float4*>(X + (size_t)(row0 + r)*Dd + k0);
    const float* xf = reinterpret_cast<const float*>(&xv);
    int swz  = (k0 >> 3) ^ (r & 7);
    int base = r*Dd + swz*8 + (k0 & 7);
    #pragma unroll
    for (int e = 0; e < 4; e++) Xt[base + e] = (short)f2bf(xf[e]);
  }
  __syncthreads();

  f32x4 acc[8];
  #pragma unroll
  for (int nf = 0; nf < 8; nf++) acc[nf] = (f32x4){0.f,0.f,0.f,0.f};

  #pragma unroll
  for (int kk = 0; kk < 4; kk++){
    int arow = wave*16 + lr;
    int swz  = (lg + kk*4) ^ (lr & 7);
    bf16x8 a = *reinterpret_cast<const bf16x8*>(&Xt[arow*Dd + swz*8]);
    #pragma unroll
    for (int nf = 0; nf < 8; nf++){
      int col  = nf*16 + lr;
      bf16x8 b = *reinterpret_cast<const bf16x8*>(&Wt[col*Dd + swz*8]);
      acc[nf] = __builtin_amdgcn_mfma_f32_16x16x32_bf16(a, b, acc[nf], 0, 0, 0);
    }
  }

  if (which < 2){
    ushort_t* out = (which == 0) ? Qb : Kb;
    #pragma unroll
    for (int nf = 0; nf < 8; nf++){
      int col = nf*16 + lr;
      float bv_ = bia[col];
      #pragma unroll
      for (int r = 0; r < 4; r++){
        int grow = row0 + wave*16 + lg*4 + r;
        out[(size_t)grow*Dd + col] = f2bf((acc[nf][r] + bv_) * sc);
      }
    }
  } else {
    __syncthreads();
    #pragma unroll
    for (int nf = 0; nf < 8; nf++){
      int col = nf*16 + lr;
      float bv_ = bia[col];
      #pragma unroll
      for (int r = 0; r < 4; r++){
        int row_l = wave*16 + lg*4 + r;
        Brot[row_l*Dd + ((col + row_l) & 127)] = acc[nf][r] + bv_;
      }
    }
    __syncthreads();
    const int bb  = row0 >> 13;
    const int tq0 = row0 & (T - 1);
    const size_t vb = (size_t)bb * Dd * T;
    #pragma unroll 4
    for (int dd = 0; dd < 32; ++dd){
      int d = wave*32 + dd;
      float v = Brot[lane*Dd + ((d + lane) & 127)];
      VbT[vb + (size_t)d*T + tq0 + lane] = f2bf(v);
    }
  }
}

// ---------------------------------------------------------------------------
// Unified per-iteration attention step. 256 threads = 4 waves; each wave owns
// a 32-row query strip (wg M-tile = 128). Swapped QK^T via 32x32x16 MFMA.
// LDS (48KB): Kt[64x128] + Vt0[128x64] + Vt1[128x64], all staged via
// global_load_lds width-16 with PRE-SWIZZLED global source (linear LDS dest):
// LDS slot (r,c) holds source 8-elem block (c ^ (r&7)).
// Online rescale: o is q-transposed (lane=d, q=crow(r,h)) -> per-register-row
// factor shuffled from lane crow(r,h). Exact max (no defer) -- required by
// the reference's ratio=new_d/d_old.
// ---------------------------------------------------------------------------
__global__ __launch_bounds__(256)
void attn_step(const ushort_t* __restrict__ Qb, const ushort_t* __restrict__ Kb,
               const ushort_t* __restrict__ VbT,
               const ushort_t* __restrict__ VcTr_hi, const ushort_t* __restrict__ VcTr_lo,
               ushort_t* __restrict__ VcTw_hi, ushort_t* __restrict__ VcTw_lo,
               float* __restrict__ VcF, float* __restrict__ m_st, float* __restrict__ d_st,
               float* __restrict__ Pacc, float* __restrict__ Pm, float* __restrict__ Pd,
               int iblk)
{
  __shared__ __align__(16) char smem[49152];
  short* Kt = (short*)smem;             // 16KB
  short* Vt0 = (short*)(smem + 16384);  // 16KB
  short* Vt1 = (short*)(smem + 32768);  // 16KB

  const int tid  = threadIdx.x;
  const int wave = tid >> 6;
  const int lane = tid & 63;
  const int l31  = lane & 31;
  const int h    = lane >> 5;

  // XCD-aware bijective swizzle (gridDim.x is always a multiple of 8)
  const int nwg = gridDim.x;
  const int bi  = (blockIdx.x & 7) * (nwg >> 3) + (blockIdx.x >> 3);

  const int g0 = Bsz * 8 * (iblk + 1);
  const bool is0 = (bi < g0);

  int b, qt, qrow0, t0, j;
  bool haslo;
  const ushort_t *qsrc, *ksrc, *vhi;

  if (is0){
    j = bi >> 6;
    int rem = bi & 63;
    b = rem >> 3; qt = rem & 7;
    qrow0 = b*T + iblk*N + qt*128;
    t0 = j*N;
    haslo = (j < iblk);
    qsrc = Qb; ksrc = Kb;
    vhi = haslo ? VcTr_hi : VbT;
  } else {
    int bi2 = bi - g0;
    int per = 8 * iblk;
    b = bi2 / per;
    int rem = bi2 - b*per;
    j = rem >> 3; qt = rem & 7;      // j = jold
    qrow0 = b*T + j*N + qt*128;
    t0 = iblk*N;
    haslo = false;
    qsrc = Kb; ksrc = Qb;
    vhi = VbT;
  }
  const int krow0base = b*T + t0;
  const size_t vbase = (size_t)b * Dd * T;
  const ushort_t* vhiB = vhi + vbase;
  const ushort_t* vloB = VcTr_lo + vbase;

  // Q fragments (B-operand): lane's q-row = qrow0 + wave*32 + l31,
  // k = ks*16 + h*8 + e  -> contiguous bf16x8 loads.
  bf16x8 qf[8];
  {
    const ushort_t* qp = qsrc + (size_t)(qrow0 + wave*32 + l31)*Dd + h*8;
    #pragma unroll
    for (int ks = 0; ks < 8; ++ks) qf[ks] = *reinterpret_cast<const bf16x8*>(qp + ks*16);
  }

  f32x16 o[4];
  #pragma unroll
  for (int db = 0; db < 4; ++db) o[db] = (f32x16)(0.0f);
  float m_run = -INFINITY;
  float d_run = 0.f;

  for (int kt = 0; kt < TPC; ++kt){
    const int krow0 = krow0base + kt*Nk;
    const int tt0   = t0 + kt*Nk;

    __syncthreads();   // previous tile fully consumed by all waves
    // --- stage K tile: 1024 x 16B blocks, pre-swizzled source, linear LDS
    {
      char* dstb = smem + (wave << 10);
      #pragma unroll
      for (int it = 0; it < 4; ++it){
        int idx = it*256 + tid;
        int r = idx >> 4, c = idx & 15;
        gl16(ksrc + (size_t)(krow0 + r)*Dd + ((c ^ (r & 7)) << 3),
             dstb + it*4096);
      }
      // --- stage V(hi) tile
      char* dstv = smem + 16384 + (wave << 10);
      #pragma unroll
      for (int it = 0; it < 4; ++it){
        int idx = it*256 + tid;
        int d = idx >> 3, sg = idx & 7;
        gl16(vhiB + (size_t)d*T + tt0 + ((sg ^ (d & 7)) << 3),
             dstv + it*4096);
      }
      if (haslo){
        char* dstl = smem + 32768 + (wave << 10);
        #pragma unroll
        for (int it = 0; it < 4; ++it){
          int idx = it*256 + tid;
          int d = idx >> 3, sg = idx & 7;
          gl16(vloB + (size_t)d*T + tt0 + ((sg ^ (d & 7)) << 3),
               dstl + it*4096);
        }
      }
    }
    __syncthreads();   // drains vmcnt before barrier

    // S^T = K · Q^T : C[kv][q], q = lane&31
    f32x16 c0 = (f32x16)(0.0f), c1 = (f32x16)(0.0f);
    __builtin_amdgcn_s_setprio(1);
    #pragma unroll
    for (int ks = 0; ks < 8; ++ks){
      int swz = (2*ks + h) ^ (l31 & 7);
      bf16x8 ka = *reinterpret_cast<const bf16x8*>(&Kt[l31*Dd + swz*8]);
      bf16x8 kb = *reinterpret_cast<const bf16x8*>(&Kt[(32 + l31)*Dd + swz*8]);
      c0 = __builtin_amdgcn_mfma_f32_32x32x16_bf16(ka, qf[ks], c0, 0, 0, 0);
      c1 = __builtin_amdgcn_mfma_f32_32x32x16_bf16(kb, qf[ks], c1, 0, 0, 0);
    }
    __builtin_amdgcn_s_setprio(0);

    // per-lane tile max over own 32 values, then sync across halves
    float tm = fmaxf(c0[0], c0[1]);
    #pragma unroll
    for (int r = 2; r < 16; r += 2) tm = fmaxf(tm, fmaxf(c0[r], c0[r+1]));
    #pragma unroll
    for (int r = 0; r < 16; r += 2) tm = fmaxf(tm, fmaxf(c1[r], c1[r+1]));
    tm = fmaxf(tm, __shfl_xor(tm, 32));

    // EXACT skip: only when no row's max grew (then scl==1 for all rows).
    // o is q-transposed (q = crow(r,h), lane = d) -> shuffle row factors.
    if (!__all(tm <= m_run)){
      float mn  = fmaxf(m_run, tm);
      float scl = exp2v(m_run - mn);   // factor for q-row l31 (this lane)
      d_run *= scl;
      m_run = mn;
      #pragma unroll
      for (int r = 0; r < 16; ++r){
        int rr = (r & 3) + 8*(r >> 2) + 4*h;
        float sr = __shfl(scl, rr);
        o[0][r] *= sr; o[1][r] *= sr; o[2][r] *= sr; o[3][r] *= sr;
      }
    }

    // p = exp2(s - m_run), in place; row-sum (per-lane row q=l31)
    float ps = 0.f;
    #pragma unroll
    for (int r = 0; r < 16; ++r){ c0[r] = exp2v(c0[r] - m_run); ps += c0[r]; }
    #pragma unroll
    for (int r = 0; r < 16; ++r){ c1[r] = exp2v(c1[r] - m_run); ps += c1[r]; }
    ps += __shfl_xor(ps, 32);
    d_run += ps;

    // pack P to bf16 words (kv order j = kvb*16 + r) and exchange halves
    uint32 w[16], wp[16];
    #pragma unroll
    for (int q = 0; q < 8; ++q){
      w[q]     = cvtpk(c0[2*q], c0[2*q+1]);
      w[8 + q] = cvtpk(c1[2*q], c1[2*q+1]);
    }
    #pragma unroll
    for (int q = 0; q < 16; ++q) wp[q] = (uint32)__shfl_xor((int)w[q], 32);

    // O += P @ V(hi)  [+ P @ V(lo) when haslo]
    __builtin_amdgcn_s_setprio(1);
    #pragma unroll
    for (int s = 0; s < 4; ++s){
      union { uint32 u[4]; bf16x8 v; } af;
      af.u[0] = h ? wp[4*s+2] : w[4*s];
      af.u[1] = h ? wp[4*s+3] : w[4*s+1];
      af.u[2] = h ? w[4*s+2]  : wp[4*s];
      af.u[3] = h ? w[4*s+3]  : wp[4*s+1];
      #pragma unroll
      for (int db = 0; db < 4; ++db){
        int swz = (2*s + h) ^ (l31 & 7);
        bf16x8 bv = *reinterpret_cast<const bf16x8*>(&Vt0[(db*32 + l31)*Nk + swz*8]);
        o[db] = __builtin_amdgcn_mfma_f32_32x32x16_bf16(af.v, bv, o[db], 0, 0, 0);
      }
      if (haslo){
        #pragma unroll
        for (int db = 0; db < 4; ++db){
          int swz = (2*s + h) ^ (l31 & 7);
          bf16x8 bv = *reinterpret_cast<const bf16x8*>(&Vt1[(db*32 + l31)*Nk + swz*8]);
          o[db] = __builtin_amdgcn_mfma_f32_32x32x16_bf16(af.v, bv, o[db], 0, 0, 0);
        }
      }
    }
    __builtin_amdgcn_s_setprio(0);
  }

  if (is0){
    // split-KV partial write: D rows = q (reg-mapped), cols = d
    const int prow_base = b*1024 + qt*128 + wave*32;
    float* pa = Pacc + (size_t)j*8192*Dd;
    #pragma unroll
    for (int r = 0; r < 16; ++r){
      int qloc = (r & 3) + 8*(r >> 2) + 4*h;
      float* row = pa + (size_t)(prow_base + qloc)*Dd + l31;
      #pragma unroll
      for (int db = 0; db < 4; ++db) row[db*32] = o[db][r];
    }
    if (lane < 32){
      Pm[j*8192 + prow_base + l31] = m_run;
      Pd[j*8192 + prow_base + l31] = d_run;
    }
  } else {
    // faithful _update_state merge, in place on VcF (log2-domain m/d)
    const int growo = qrow0 + wave*32 + l31;
    float mo_o = m_st[growo], do_o = d_st[growo];
    float mn_o = fmaxf(mo_o, m_run);
    float nd_o = do_o * exp2v(mo_o - mn_o) + d_run * exp2v(m_run - mn_o);

    #pragma unroll
    for (int r = 0; r < 16; ++r){
      int rr = (r & 3) + 8*(r >> 2) + 4*h;
      float m_r  = __shfl(m_run, rr);
      float d_r  = __shfl(d_run, rr);
      float mo   = __shfl(mo_o, rr);
      float dold = __shfl(do_o, rr);
      float mn = fmaxf(mo, m_r);
      float se = exp2v(m_r - mn);
      float nd = dold * exp2v(mo - mn) + d_r * se;
      float ratio = nd / dold;
      float accm  = se / nd;
      size_t base = (size_t)(qrow0 + wave*32 + rr)*Dd + l31;
      #pragma unroll
      for (int db = 0; db < 4; ++db){
        float v = ratio * VcF[base + db*32] + o[db][r] * accm;
        VcF[base + db*32] = v;
        o[db][r] = v;
      }
    }
    if (lane < 32){ m_st[growo] = mn_o; d_st[growo] = nd_o; }

    // bounce-transpose updated rows into VcT(write) hi/lo -- bf16 rounds,
    // per-wave 8KB region (no cross-wave sharing -> single barrier).
    __syncthreads();   // all waves done with Kt/Vt
    ushort_t* brot = (ushort_t*)smem + wave*4096;   // 32 rows x 128, rotated
    const int tabs = (qrow0 - b*T) + wave*32 + l31;
    // hi round
    #pragma unroll
    for (int r = 0; r < 16; ++r){
      int rr = (r & 3) + 8*(r >> 2) + 4*h;
      #pragma unroll
      for (int db = 0; db < 4; ++db){
        int d = db*32 + l31;
        brot[rr*128 + ((d + rr) & 127)] = f2bf(o[db][r]);
      }
    }
    #pragma unroll 4
    for (int dd = 0; dd < 64; ++dd){
      int d = dd*2 + h;
      VcTw_hi[vbase + (size_t)d*T + tabs] = brot[l31*128 + ((d + l31) & 127)];
    }
    // lo round (same-wave region reuse; HW orders per-wave LDS ops)
    #pragma unroll
    for (int r = 0; r < 16; ++r){
      int rr = (r & 3) + 8*(r >> 2) + 4*h;
      #pragma unroll
      for (int db = 0; db < 4; ++db){
        int d = db*32 + l31;
        float v = o[db][r];
        brot[rr*128 + ((d + rr) & 127)] = f2bf(v - bf2f(f2bf(v)));
      }
    }
    #pragma unroll 4
    for (int dd = 0; dd < 64; ++dd){
      int d = dd*2 + h;
      VcTw_lo[vbase + (size_t)d*T + tabs] = brot[l31*128 + ((d + l31) & 127)];
    }
  }
}

// ---------------------------------------------------------------------------
// Merge split-KV partials -> block iblk rows of VcF, m_st, d_st, VcT(write).
// grid = 128 (b, qt64), 256 threads. log2-domain m/d.
// ---------------------------------------------------------------------------
__global__ __launch_bounds__(256)
void merge_kernel(const float* __restrict__ Pacc, const float* __restrict__ Pm,
                  const float* __restrict__ Pd,
                  float* __restrict__ VcF, float* __restrict__ m_st, float* __restrict__ d_st,
                  ushort_t* __restrict__ VcTw_hi, ushort_t* __restrict__ VcTw_lo,
                  int iblk)
{
  __shared__ float Brot[64*Dd];   // 32KB rotation layout
  const int bi = blockIdx.x;
  const int b = bi >> 4, qt = bi & 15;
  const int tid = threadIdx.x;
  const int lrow = tid >> 2, dq = tid & 3;
  const int prow = b*1024 + qt*64 + lrow;
  const int grow = b*T + iblk*N + qt*64 + lrow;

  float M = -INFINITY;
  for (int jj = 0; jj <= iblk; ++jj) M = fmaxf(M, Pm[jj*8192 + prow]);

  float out[32];
  #pragma unroll
  for (int e = 0; e < 32; ++e) out[e] = 0.f;
  float D = 0.f;
  for (int jj = 0; jj <= iblk; ++jj){
    float wj = exp2v(Pm[jj*8192 + prow] - M);
    D += Pd[jj*8192 + prow] * wj;
    const float* pa = Pacc + ((size_t)jj*8192 + prow)*Dd + dq*32;
    #pragma unroll
    for (int e8 = 0; e8 < 8; ++e8){
      float4 v = *reinterpret_cast<const float4*>(pa + e8*4);
      out[e8*4+0] += v.x * wj;
      out[e8*4+1] += v.y * wj;
      out[e8*4+2] += v.z * wj;
      out[e8*4+3] += v.w * wj;
    }
  }
  float dinv = 1.f / D;
  #pragma unroll
  for (int e = 0; e < 32; ++e){
    int d = dq*32 + e;
    float v = out[e] * dinv;
    VcF[(size_t)grow*Dd + d] = v;
    Brot[lrow*Dd + ((d + lrow) & 127)] = v;
  }
  if (dq == 0){ m_st[grow] = M; d_st[grow] = D; }
  __syncthreads();

  const int wave = tid >> 6, lane = tid & 63;
  const int tq0 = iblk*N + qt*64;
  const size_t vb = (size_t)b * Dd * T;
  #pragma unroll 4
  for (int dd = 0; dd < 32; ++dd){
    int d = wave*32 + dd;
    float v = Brot[lane*Dd + ((d + lane) & 127)];
    ushort_t hi = f2bf(v);
    VcTw_hi[vb + (size_t)d*T + tq0 + lane] = hi;
    VcTw_lo[vb + (size_t)d*T + tq0 + lane] = f2bf(v - bf2f(hi));
  }
}

// ---------------------------------------------------------------------------
extern "C" void kernel_launch(void* const* d_in, const int* in_sizes, int n_in,
                              void* d_out, int out_size, void* d_ws, size_t ws_size,
                              hipStream_t stream)
{
  (void)in_sizes; (void)n_in; (void)out_size; (void)ws_size;

  const float* x  = (const float*)d_in[0];
  const float* Wq = (const float*)d_in[1];
  const float* bq = (const float*)d_in[2];
  const float* Wk = (const float*)d_in[3];
  const float* bk = (const float*)d_in[4];
  const float* Wv = (const float*)d_in[5];
  const float* bv = (const float*)d_in[6];

  float* VcF = (float*)d_out;          // fp32 master v_cache == output

  const size_t nt = (size_t)Bsz * T;   // 65536 rows
  char* p = (char*)d_ws;
  auto alloc = [&](size_t bytes) -> void* {
    void* r = (void*)p;
    p += (bytes + 255) & ~(size_t)255;
    return r;
  };
  ushort_t* Qb   = (ushort_t*)alloc(nt * Dd * 2);          // 16MB
  ushort_t* Kb   = (ushort_t*)alloc(nt * Dd * 2);          // 16MB
  ushort_t* VbT  = (ushort_t*)alloc(nt * Dd * 2);          // 16MB transposed raw V
  ushort_t* VcT[2][2];
  for (int c = 0; c < 2; ++c)
    for (int hh = 0; hh < 2; ++hh)
      VcT[c][hh] = (ushort_t*)alloc(nt * Dd * 2);          // 4 x 16MB
  float* m_st = (float*)alloc(nt * 4);
  float* d_st = (float*)alloc(nt * 4);
  float* Pacc = (float*)alloc((size_t)NB * 8192 * Dd * 4); // 33.5MB
  float* Pm   = (float*)alloc((size_t)NB * 8192 * 4);
  float* Pd   = (float*)alloc((size_t)NB * 8192 * 4);

  // 1/sqrt(128) * log2(e): scores computed directly in log2 domain
  const float scale = 0.08838834764831845f * 1.4426950408889634f;
  dim3 blk(256);

  proj_kernel<<<dim3((unsigned)(nt / 64), 3), blk, 0, stream>>>(
      x, Wq, bq, Wk, bk, Wv, bv, Qb, Kb, VbT, scale);

  for (int i = 0; i < NB; ++i){
    const int wb = i & 1, rb = wb ^ 1;
    const int grid = 64 * (2*i + 1);
    attn_step<<<grid, blk, 0, stream>>>(
        Qb, Kb, VbT,
        VcT[rb][0], VcT[rb][1], VcT[wb][0], VcT[wb][1],
        VcF, m_st, d_st, Pacc, Pm, Pd, i);
    merge_kernel<<<128, blk, 0, stream>>>(
        Pacc, Pm, Pd, VcF, m_st, d_st, VcT[wb][0], VcT[wb][1], i);
  }
}

// Round 7
// 1027.830 us; speedup vs baseline: 1.2868x; 1.1226x over previous
//
#include <hip/hip_runtime.h>

typedef __attribute__((ext_vector_type(8))) short bf16x8;
typedef __attribute__((ext_vector_type(4))) float f32x4;
typedef __attribute__((ext_vector_type(16))) float f32x16;
typedef unsigned short ushort_t;
typedef unsigned int uint32;

static constexpr int Bsz = 8;       // batch
static constexpr int T   = 8192;    // sequence length
static constexpr int Dd  = 128;     // head dim
static constexpr int NB  = 8;       // chunks
static constexpr int N   = T / NB;  // 1024 tokens per chunk
static constexpr int Nk  = 64;      // keys per tile
static constexpr int TPC = N / Nk;  // 16 tiles per chunk

__device__ __forceinline__ float bf2f(ushort_t u){
  return __uint_as_float(((uint32)u) << 16);
}
__device__ __forceinline__ ushort_t f2bf(float f){
  uint32 u = __float_as_uint(f);
  u += 0x7FFFu + ((u >> 16) & 1u);   // RNE
  return (ushort_t)(u >> 16);
}
// HW packed f32->bf16 (RNE): dst.lo16 = bf16(a), dst.hi16 = bf16(b)
__device__ __forceinline__ uint32 cvtpk(float a, float b){
  uint32 r;
  asm("v_cvt_pk_bf16_f32 %0, %1, %2" : "=v"(r) : "v"(a), "v"(b));
  return r;
}
__device__ __forceinline__ float exp2v(float x){
  float r;
  asm("v_exp_f32 %0, %1" : "=v"(r) : "v"(x));
  return r;
}
typedef __attribute__((address_space(1))) const unsigned int guint;
typedef __attribute__((address_space(3))) unsigned int luint;
__device__ __forceinline__ void gl16(const void* g, void* l){
  __builtin_amdgcn_global_load_lds((guint*)g, (luint*)l, 16, 0, 0);
}

// ---------------------------------------------------------------------------
// Projection: grid (nt/64, 3).  y=0: Qb=(XWq+bq)*scale*log2e row-major bf16
//                               y=1: Kb=(XWk+bk) row-major bf16
//                               y=2: VbT=(XWv+bv) TRANSPOSED [b][d][t] bf16
// ---------------------------------------------------------------------------
__global__ __launch_bounds__(256)
void proj_kernel(const float* __restrict__ X,
                 const float* __restrict__ Wq, const float* __restrict__ bq,
                 const float* __restrict__ Wk, const float* __restrict__ bk,
                 const float* __restrict__ Wv, const float* __restrict__ bv,
                 ushort_t* __restrict__ Qb, ushort_t* __restrict__ Kb,
                 ushort_t* __restrict__ VbT, float scale)
{
  __shared__ __align__(16) char smem[49152];
  short* Xt = (short*)smem;             // 16KB [64][128] swz
  short* Wt = (short*)(smem + 16384);   // 32KB [col][k] swz
  float* Brot = (float*)smem;           // 32KB overlay (V bounce)

  const int which = blockIdx.y;
  const float* W   = (which == 0) ? Wq : (which == 1) ? Wk : Wv;
  const float* bia = (which == 0) ? bq : (which == 1) ? bk : bv;
  const float sc   = (which == 0) ? scale : 1.0f;

  const int tid  = threadIdx.x;
  const int wave = tid >> 6;
  const int lane = tid & 63;
  const int lg   = lane >> 4;
  const int lr   = lane & 15;
  const int row0 = blockIdx.x * 64;

  for (int c = tid; c < Dd*32; c += 256){
    int k  = c >> 5;
    int j0 = (c & 31) * 4;
    const float4 w = *reinterpret_cast<const float4*>(W + (size_t)k*Dd + j0);
    const float* wf = reinterpret_cast<const float*>(&w);
    #pragma unroll
    for (int e = 0; e < 4; e++){
      int jj = j0 + e;
      int inner = (k & 7) | (((k >> 3) ^ (jj & 7)) << 3);
      Wt[jj*Dd + inner] = (short)f2bf(wf[e]);
    }
  }
  for (int c = tid; c < 64*32; c += 256){
    int r  = c >> 5;
    int k0 = (c & 31) * 4;
    const float4 xv = *reinterpret_cast<const float4*>(X + (size_t)(row0 + r)*Dd + k0);
    const float* xf = reinterpret_cast<const float*>(&xv);
    int swz  = (k0 >> 3) ^ (r & 7);
    int base = r*Dd + swz*8 + (k0 & 7);
    #pragma unroll
    for (int e = 0; e < 4; e++) Xt[base + e] = (short)f2bf(xf[e]);
  }
  __syncthreads();

  f32x4 acc[8];
  #pragma unroll
  for (int nf = 0; nf < 8; nf++) acc[nf] = (f32x4){0.f,0.f,0.f,0.f};

  #pragma unroll
  for (int kk = 0; kk < 4; kk++){
    int arow = wave*16 + lr;
    int swz  = (lg + kk*4) ^ (lr & 7);
    bf16x8 a = *reinterpret_cast<const bf16x8*>(&Xt[arow*Dd + swz*8]);
    #pragma unroll
    for (int nf = 0; nf < 8; nf++){
      int col  = nf*16 + lr;
      bf16x8 b = *reinterpret_cast<const bf16x8*>(&Wt[col*Dd + swz*8]);
      acc[nf] = __builtin_amdgcn_mfma_f32_16x16x32_bf16(a, b, acc[nf], 0, 0, 0);
    }
  }

  if (which < 2){
    ushort_t* out = (which == 0) ? Qb : Kb;
    #pragma unroll
    for (int nf = 0; nf < 8; nf++){
      int col = nf*16 + lr;
      float bv_ = bia[col];
      #pragma unroll
      for (int r = 0; r < 4; r++){
        int grow = row0 + wave*16 + lg*4 + r;
        out[(size_t)grow*Dd + col] = f2bf((acc[nf][r] + bv_) * sc);
      }
    }
  } else {
    __syncthreads();
    #pragma unroll
    for (int nf = 0; nf < 8; nf++){
      int col = nf*16 + lr;
      float bv_ = bia[col];
      #pragma unroll
      for (int r = 0; r < 4; r++){
        int row_l = wave*16 + lg*4 + r;
        Brot[row_l*Dd + ((col + row_l) & 127)] = acc[nf][r] + bv_;
      }
    }
    __syncthreads();
    const int bb  = row0 >> 13;
    const int tq0 = row0 & (T - 1);
    const size_t vb = (size_t)bb * Dd * T;
    #pragma unroll 4
    for (int dd = 0; dd < 32; ++dd){
      int d = wave*32 + dd;
      float v = Brot[lane*Dd + ((d + lane) & 127)];
      VbT[vb + (size_t)d*T + tq0 + lane] = f2bf(v);
    }
  }
}

// ---------------------------------------------------------------------------
// Unified per-iteration attention step. 256 threads = 4 waves; each wave owns
// a 32-row query strip (wg M-tile = 128). Swapped QK^T via 32x32x16 MFMA.
// LDS: DOUBLE-BUFFERED 2 x (Kt 16KB + Vt 16KB) = 64KB, staged via
// global_load_lds width-16 with pre-swizzled global source + linear LDS dest.
// 2-phase pipeline: issue STAGE(t+1) -> compute(t) -> vmcnt(0)+barrier.
// Value cache read as SINGLE bf16 (VcT); fp32 master VcF is the only
// accumulating state, so bf16-V error does not compound.
// Online rescale: o is q-transposed (lane=d, q=crow(r,h)) -> per-register-row
// factor shuffled from lane crow(r,h). Exact max (no defer) -- required by
// the reference's ratio=new_d/d_old.
// ---------------------------------------------------------------------------
__global__ __launch_bounds__(256)
void attn_step(const ushort_t* __restrict__ Qb, const ushort_t* __restrict__ Kb,
               const ushort_t* __restrict__ VbT,
               const ushort_t* __restrict__ VcTr, ushort_t* __restrict__ VcTw,
               float* __restrict__ VcF, float* __restrict__ m_st, float* __restrict__ d_st,
               float* __restrict__ Pacc, float* __restrict__ Pm, float* __restrict__ Pd,
               int iblk)
{
  __shared__ __align__(16) char smem[65536];   // 2 x (K 16KB + V 16KB)

  const int tid  = threadIdx.x;
  const int wave = tid >> 6;
  const int lane = tid & 63;
  const int l31  = lane & 31;
  const int h    = lane >> 5;

  // XCD-aware bijective swizzle (gridDim.x is always a multiple of 8)
  const int nwg = gridDim.x;
  const int bi  = (blockIdx.x & 7) * (nwg >> 3) + (blockIdx.x >> 3);

  const int g0 = Bsz * 8 * (iblk + 1);
  const bool is0 = (bi < g0);

  int b, qt, qrow0, t0, j;
  const ushort_t *qsrc, *ksrc, *vhi;

  if (is0){
    j = bi >> 6;
    int rem = bi & 63;
    b = rem >> 3; qt = rem & 7;
    qrow0 = b*T + iblk*N + qt*128;
    t0 = j*N;
    qsrc = Qb; ksrc = Kb;
    vhi = (j < iblk) ? VcTr : VbT;
  } else {
    int bi2 = bi - g0;
    int per = 8 * iblk;
    b = bi2 / per;
    int rem = bi2 - b*per;
    j = rem >> 3; qt = rem & 7;      // j = jold
    qrow0 = b*T + j*N + qt*128;
    t0 = iblk*N;
    qsrc = Kb; ksrc = Qb;
    vhi = VbT;
  }
  const int krow0base = b*T + t0;
  const size_t vbase = (size_t)b * Dd * T;
  const ushort_t* vhiB = vhi + vbase;

  // Per-thread staging source pointers (advance by constant stride per tile).
  // K: thread covers (r = tid>>4, c-block = tid&15), slot src = c ^ (r&7).
  // V: thread covers (d = tid>>3, sg = tid&7),      slot src = sg ^ (d&7).
  const ushort_t* kp = ksrc + (size_t)(krow0base + (tid >> 4))*Dd
                            + (((tid & 15) ^ ((tid >> 4) & 7)) << 3);
  const ushort_t* vp = vhiB + (size_t)(tid >> 3)*T + t0
                            + (((tid & 7) ^ ((tid >> 3) & 7)) << 3);

  auto STAGE = [&](const ushort_t* kpp, const ushort_t* vpp, int bufi){
    char* dstb = smem + bufi*32768 + (wave << 10);
    char* dstv = dstb + 16384;
    #pragma unroll
    for (int it = 0; it < 4; ++it){
      gl16(kpp + it*16*Dd, dstb + it*4096);            // +16 rows per chunk
      gl16(vpp + (size_t)it*32*T, dstv + it*4096);     // +32 d-rows per chunk
    }
  };

  // Q fragments (B-operand): lane's q-row = qrow0 + wave*32 + l31,
  // k = ks*16 + h*8 + e  -> contiguous bf16x8 loads.
  bf16x8 qf[8];
  {
    const ushort_t* qp = qsrc + (size_t)(qrow0 + wave*32 + l31)*Dd + h*8;
    #pragma unroll
    for (int ks = 0; ks < 8; ++ks) qf[ks] = *reinterpret_cast<const bf16x8*>(qp + ks*16);
  }

  f32x16 o[4];
  #pragma unroll
  for (int db = 0; db < 4; ++db) o[db] = (f32x16)(0.0f);
  float m_run = -INFINITY;
  float d_run = 0.f;

  STAGE(kp, vp, 0);
  __syncthreads();             // vmcnt(0) + barrier: buf0 ready
  int cur = 0;

  for (int kt = 0; kt < TPC; ++kt){
    if (kt + 1 < TPC){
      kp += 64*Dd; vp += 64;
      STAGE(kp, vp, cur ^ 1);  // async: lands during compute below
    }
    const short* Kt  = (const short*)(smem + cur*32768);
    const short* Vt0 = (const short*)(smem + cur*32768 + 16384);

    // S^T = K · Q^T : C[kv][q], q = lane&31
    f32x16 c0 = (f32x16)(0.0f), c1 = (f32x16)(0.0f);
    __builtin_amdgcn_s_setprio(1);
    #pragma unroll
    for (int ks = 0; ks < 8; ++ks){
      int swz = (2*ks + h) ^ (l31 & 7);
      bf16x8 ka = *reinterpret_cast<const bf16x8*>(&Kt[l31*Dd + swz*8]);
      bf16x8 kb = *reinterpret_cast<const bf16x8*>(&Kt[(32 + l31)*Dd + swz*8]);
      c0 = __builtin_amdgcn_mfma_f32_32x32x16_bf16(ka, qf[ks], c0, 0, 0, 0);
      c1 = __builtin_amdgcn_mfma_f32_32x32x16_bf16(kb, qf[ks], c1, 0, 0, 0);
    }
    __builtin_amdgcn_s_setprio(0);

    // per-lane tile max over own 32 values, then sync across halves
    float tm = fmaxf(c0[0], c0[1]);
    #pragma unroll
    for (int r = 2; r < 16; r += 2) tm = fmaxf(tm, fmaxf(c0[r], c0[r+1]));
    #pragma unroll
    for (int r = 0; r < 16; r += 2) tm = fmaxf(tm, fmaxf(c1[r], c1[r+1]));
    tm = fmaxf(tm, __shfl_xor(tm, 32));

    // EXACT skip: only when no row's max grew (then scl==1 for all rows).
    // o is q-transposed (q = crow(r,h), lane = d) -> shuffle row factors.
    if (!__all(tm <= m_run)){
      float mn  = fmaxf(m_run, tm);
      float scl = exp2v(m_run - mn);   // factor for q-row l31 (this lane)
      d_run *= scl;
      m_run = mn;
      #pragma unroll
      for (int r = 0; r < 16; ++r){
        int rr = (r & 3) + 8*(r >> 2) + 4*h;
        float sr = __shfl(scl, rr);
        o[0][r] *= sr; o[1][r] *= sr; o[2][r] *= sr; o[3][r] *= sr;
      }
    }

    // p = exp2(s - m_run), in place; row-sum (per-lane row q=l31)
    float ps = 0.f;
    #pragma unroll
    for (int r = 0; r < 16; ++r){ c0[r] = exp2v(c0[r] - m_run); ps += c0[r]; }
    #pragma unroll
    for (int r = 0; r < 16; ++r){ c1[r] = exp2v(c1[r] - m_run); ps += c1[r]; }
    ps += __shfl_xor(ps, 32);
    d_run += ps;

    // pack P to bf16 words (kv order j = kvb*16 + r) and exchange halves
    uint32 w[16], wp[16];
    #pragma unroll
    for (int q = 0; q < 8; ++q){
      w[q]     = cvtpk(c0[2*q], c0[2*q+1]);
      w[8 + q] = cvtpk(c1[2*q], c1[2*q+1]);
    }
    #pragma unroll
    for (int q = 0; q < 16; ++q) wp[q] = (uint32)__shfl_xor((int)w[q], 32);

    // O += P @ V
    __builtin_amdgcn_s_setprio(1);
    #pragma unroll
    for (int s = 0; s < 4; ++s){
      union { uint32 u[4]; bf16x8 v; } af;
      af.u[0] = h ? wp[4*s+2] : w[4*s];
      af.u[1] = h ? wp[4*s+3] : w[4*s+1];
      af.u[2] = h ? w[4*s+2]  : wp[4*s];
      af.u[3] = h ? w[4*s+3]  : wp[4*s+1];
      #pragma unroll
      for (int db = 0; db < 4; ++db){
        int swz = (2*s + h) ^ (l31 & 7);
        bf16x8 bv = *reinterpret_cast<const bf16x8*>(&Vt0[(db*32 + l31)*Nk + swz*8]);
        o[db] = __builtin_amdgcn_mfma_f32_32x32x16_bf16(af.v, bv, o[db], 0, 0, 0);
      }
    }
    __builtin_amdgcn_s_setprio(0);

    __syncthreads();   // drains vmcnt (stage t+1) + all waves done with buf cur
    cur ^= 1;
  }

  if (is0){
    // split-KV partial write: D rows = q (reg-mapped), cols = d
    const int prow_base = b*1024 + qt*128 + wave*32;
    float* pa = Pacc + (size_t)j*8192*Dd;
    #pragma unroll
    for (int r = 0; r < 16; ++r){
      int qloc = (r & 3) + 8*(r >> 2) + 4*h;
      float* row = pa + (size_t)(prow_base + qloc)*Dd + l31;
      #pragma unroll
      for (int db = 0; db < 4; ++db) row[db*32] = o[db][r];
    }
    if (lane < 32){
      Pm[j*8192 + prow_base + l31] = m_run;
      Pd[j*8192 + prow_base + l31] = d_run;
    }
  } else {
    // faithful _update_state merge, in place on VcF (log2-domain m/d)
    const int growo = qrow0 + wave*32 + l31;
    float mo_o = m_st[growo], do_o = d_st[growo];
    float mn_o = fmaxf(mo_o, m_run);
    float nd_o = do_o * exp2v(mo_o - mn_o) + d_run * exp2v(m_run - mn_o);

    #pragma unroll
    for (int r = 0; r < 16; ++r){
      int rr = (r & 3) + 8*(r >> 2) + 4*h;
      float m_r  = __shfl(m_run, rr);
      float d_r  = __shfl(d_run, rr);
      float mo   = __shfl(mo_o, rr);
      float dold = __shfl(do_o, rr);
      float mn = fmaxf(mo, m_r);
      float se = exp2v(m_r - mn);
      float nd = dold * exp2v(mo - mn) + d_r * se;
      float ratio = nd / dold;
      float accm  = se / nd;
      size_t base = (size_t)(qrow0 + wave*32 + rr)*Dd + l31;
      #pragma unroll
      for (int db = 0; db < 4; ++db){
        float v = ratio * VcF[base + db*32] + o[db][r] * accm;
        VcF[base + db*32] = v;
        o[db][r] = v;
      }
    }
    if (lane < 32){ m_st[growo] = mn_o; d_st[growo] = nd_o; }

    // bounce-transpose updated rows into VcT(write), bf16, per-wave 8KB
    // region (loop's final barrier already synced; regions are disjoint).
    ushort_t* brot = (ushort_t*)smem + wave*4096;   // 32 rows x 128, rotated
    const int tabs = (qrow0 - b*T) + wave*32 + l31;
    #pragma unroll
    for (int r = 0; r < 16; ++r){
      int rr = (r & 3) + 8*(r >> 2) + 4*h;
      #pragma unroll
      for (int db = 0; db < 4; ++db){
        int d = db*32 + l31;
        brot[rr*128 + ((d + rr) & 127)] = f2bf(o[db][r]);
      }
    }
    #pragma unroll 4
    for (int dd = 0; dd < 64; ++dd){
      int d = dd*2 + h;
      VcTw[vbase + (size_t)d*T + tabs] = brot[l31*128 + ((d + l31) & 127)];
    }
  }
}

// ---------------------------------------------------------------------------
// Merge split-KV partials -> block iblk rows of VcF, m_st, d_st, VcT(write).
// grid = 128 (b, qt64), 256 threads. log2-domain m/d.
// ---------------------------------------------------------------------------
__global__ __launch_bounds__(256)
void merge_kernel(const float* __restrict__ Pacc, const float* __restrict__ Pm,
                  const float* __restrict__ Pd,
                  float* __restrict__ VcF, float* __restrict__ m_st, float* __restrict__ d_st,
                  ushort_t* __restrict__ VcTw, int iblk)
{
  __shared__ float Brot[64*Dd];   // 32KB rotation layout
  const int bi = blockIdx.x;
  const int b = bi >> 4, qt = bi & 15;
  const int tid = threadIdx.x;
  const int lrow = tid >> 2, dq = tid & 3;
  const int prow = b*1024 + qt*64 + lrow;
  const int grow = b*T + iblk*N + qt*64 + lrow;

  float M = -INFINITY;
  for (int jj = 0; jj <= iblk; ++jj) M = fmaxf(M, Pm[jj*8192 + prow]);

  float out[32];
  #pragma unroll
  for (int e = 0; e < 32; ++e) out[e] = 0.f;
  float D = 0.f;
  for (int jj = 0; jj <= iblk; ++jj){
    float wj = exp2v(Pm[jj*8192 + prow] - M);
    D += Pd[jj*8192 + prow] * wj;
    const float* pa = Pacc + ((size_t)jj*8192 + prow)*Dd + dq*32;
    #pragma unroll
    for (int e8 = 0; e8 < 8; ++e8){
      float4 v = *reinterpret_cast<const float4*>(pa + e8*4);
      out[e8*4+0] += v.x * wj;
      out[e8*4+1] += v.y * wj;
      out[e8*4+2] += v.z * wj;
      out[e8*4+3] += v.w * wj;
    }
  }
  float dinv = 1.f / D;
  #pragma unroll
  for (int e = 0; e < 32; ++e){
    int d = dq*32 + e;
    float v = out[e] * dinv;
    VcF[(size_t)grow*Dd + d] = v;
    Brot[lrow*Dd + ((d + lrow) & 127)] = v;
  }
  if (dq == 0){ m_st[grow] = M; d_st[grow] = D; }
  __syncthreads();

  const int wave = tid >> 6, lane = tid & 63;
  const int tq0 = iblk*N + qt*64;
  const size_t vb = (size_t)b * Dd * T;
  #pragma unroll 4
  for (int dd = 0; dd < 32; ++dd){
    int d = wave*32 + dd;
    float v = Brot[lane*Dd + ((d + lane) & 127)];
    VcTw[vb + (size_t)d*T + tq0 + lane] = f2bf(v);
  }
}

// ---------------------------------------------------------------------------
extern "C" void kernel_launch(void* const* d_in, const int* in_sizes, int n_in,
                              void* d_out, int out_size, void* d_ws, size_t ws_size,
                              hipStream_t stream)
{
  (void)in_sizes; (void)n_in; (void)out_size; (void)ws_size;

  const float* x  = (const float*)d_in[0];
  const float* Wq = (const float*)d_in[1];
  const float* bq = (const float*)d_in[2];
  const float* Wk = (const float*)d_in[3];
  const float* bk = (const float*)d_in[4];
  const float* Wv = (const float*)d_in[5];
  const float* bv = (const float*)d_in[6];

  float* VcF = (float*)d_out;          // fp32 master v_cache == output

  const size_t nt = (size_t)Bsz * T;   // 65536 rows
  char* p = (char*)d_ws;
  auto alloc = [&](size_t bytes) -> void* {
    void* r = (void*)p;
    p += (bytes + 255) & ~(size_t)255;
    return r;
  };
  ushort_t* Qb   = (ushort_t*)alloc(nt * Dd * 2);          // 16MB
  ushort_t* Kb   = (ushort_t*)alloc(nt * Dd * 2);          // 16MB
  ushort_t* VbT  = (ushort_t*)alloc(nt * Dd * 2);          // 16MB transposed raw V
  ushort_t* VcT[2];
  for (int c = 0; c < 2; ++c)
    VcT[c] = (ushort_t*)alloc(nt * Dd * 2);                // 2 x 16MB
  float* m_st = (float*)alloc(nt * 4);
  float* d_st = (float*)alloc(nt * 4);
  float* Pacc = (float*)alloc((size_t)NB * 8192 * Dd * 4); // 33.5MB
  float* Pm   = (float*)alloc((size_t)NB * 8192 * 4);
  float* Pd   = (float*)alloc((size_t)NB * 8192 * 4);

  // 1/sqrt(128) * log2(e): scores computed directly in log2 domain
  const float scale = 0.08838834764831845f * 1.4426950408889634f;
  dim3 blk(256);

  proj_kernel<<<dim3((unsigned)(nt / 64), 3), blk, 0, stream>>>(
      x, Wq, bq, Wk, bk, Wv, bv, Qb, Kb, VbT, scale);

  for (int i = 0; i < NB; ++i){
    const int wb = i & 1, rb = wb ^ 1;
    const int grid = 64 * (2*i + 1);
    attn_step<<<grid, blk, 0, stream>>>(
        Qb, Kb, VbT, VcT[rb], VcT[wb],
        VcF, m_st, d_st, Pacc, Pm, Pd, i);
    merge_kernel<<<128, blk, 0, stream>>>(
        Pacc, Pm, Pd, VcF, m_st, d_st, VcT[wb], i);
  }
}

// Round 8
// 740.659 us; speedup vs baseline: 1.7857x; 1.3877x over previous
//
#include <hip/hip_runtime.h>

typedef __attribute__((ext_vector_type(8))) short bf16x8;
typedef __attribute__((ext_vector_type(4))) float f32x4;
typedef __attribute__((ext_vector_type(16))) float f32x16;
typedef unsigned short ushort_t;
typedef unsigned int uint32;

static constexpr int Bsz = 8;       // batch
static constexpr int T   = 8192;    // sequence length
static constexpr int Dd  = 128;     // head dim
static constexpr int NB  = 8;       // chunks
static constexpr int N   = T / NB;  // 1024 tokens per chunk
static constexpr int Nk  = 64;      // keys per tile
static constexpr int TPC = N / Nk;  // 16 tiles per chunk

__device__ __forceinline__ float bf2f(ushort_t u){
  return __uint_as_float(((uint32)u) << 16);
}
__device__ __forceinline__ ushort_t f2bf(float f){
  uint32 u = __float_as_uint(f);
  u += 0x7FFFu + ((u >> 16) & 1u);   // RNE
  return (ushort_t)(u >> 16);
}
// HW packed f32->bf16 (RNE): dst.lo16 = bf16(a), dst.hi16 = bf16(b)
__device__ __forceinline__ uint32 cvtpk(float a, float b){
  uint32 r;
  asm("v_cvt_pk_bf16_f32 %0, %1, %2" : "=v"(r) : "v"(a), "v"(b));
  return r;
}
__device__ __forceinline__ float exp2v(float x){
  float r;
  asm("v_exp_f32 %0, %1" : "=v"(r) : "v"(x));
  return r;
}
typedef __attribute__((address_space(1))) const unsigned int guint;
typedef __attribute__((address_space(3))) unsigned int luint;
__device__ __forceinline__ void gl16(const void* g, void* l){
  __builtin_amdgcn_global_load_lds((guint*)g, (luint*)l, 16, 0, 0);
}

// ---------------------------------------------------------------------------
// Projection: grid (nt/64, 3).  y=0: Qb=(XWq+bq)*scale*log2e row-major bf16
//                               y=1: Kb=(XWk+bk) row-major bf16
//                               y=2: VbT=(XWv+bv) TRANSPOSED [b][d][t] bf16
// ---------------------------------------------------------------------------
__global__ __launch_bounds__(256)
void proj_kernel(const float* __restrict__ X,
                 const float* __restrict__ Wq, const float* __restrict__ bq,
                 const float* __restrict__ Wk, const float* __restrict__ bk,
                 const float* __restrict__ Wv, const float* __restrict__ bv,
                 ushort_t* __restrict__ Qb, ushort_t* __restrict__ Kb,
                 ushort_t* __restrict__ VbT, float scale)
{
  __shared__ __align__(16) char smem[49152];
  short* Xt = (short*)smem;             // 16KB [64][128] swz
  short* Wt = (short*)(smem + 16384);   // 32KB [col][k] swz
  float* Brot = (float*)smem;           // 32KB overlay (V bounce)

  const int which = blockIdx.y;
  const float* W   = (which == 0) ? Wq : (which == 1) ? Wk : Wv;
  const float* bia = (which == 0) ? bq : (which == 1) ? bk : bv;
  const float sc   = (which == 0) ? scale : 1.0f;

  const int tid  = threadIdx.x;
  const int wave = tid >> 6;
  const int lane = tid & 63;
  const int lg   = lane >> 4;
  const int lr   = lane & 15;
  const int row0 = blockIdx.x * 64;

  for (int c = tid; c < Dd*32; c += 256){
    int k  = c >> 5;
    int j0 = (c & 31) * 4;
    const float4 w = *reinterpret_cast<const float4*>(W + (size_t)k*Dd + j0);
    const float* wf = reinterpret_cast<const float*>(&w);
    #pragma unroll
    for (int e = 0; e < 4; e++){
      int jj = j0 + e;
      int inner = (k & 7) | (((k >> 3) ^ (jj & 7)) << 3);
      Wt[jj*Dd + inner] = (short)f2bf(wf[e]);
    }
  }
  for (int c = tid; c < 64*32; c += 256){
    int r  = c >> 5;
    int k0 = (c & 31) * 4;
    const float4 xv = *reinterpret_cast<const float4*>(X + (size_t)(row0 + r)*Dd + k0);
    const float* xf = reinterpret_cast<const float*>(&xv);
    int swz  = (k0 >> 3) ^ (r & 7);
    int base = r*Dd + swz*8 + (k0 & 7);
    #pragma unroll
    for (int e = 0; e < 4; e++) Xt[base + e] = (short)f2bf(xf[e]);
  }
  __syncthreads();

  f32x4 acc[8];
  #pragma unroll
  for (int nf = 0; nf < 8; nf++) acc[nf] = (f32x4){0.f,0.f,0.f,0.f};

  #pragma unroll
  for (int kk = 0; kk < 4; kk++){
    int arow = wave*16 + lr;
    int swz  = (lg + kk*4) ^ (lr & 7);
    bf16x8 a = *reinterpret_cast<const bf16x8*>(&Xt[arow*Dd + swz*8]);
    #pragma unroll
    for (int nf = 0; nf < 8; nf++){
      int col  = nf*16 + lr;
      bf16x8 b = *reinterpret_cast<const bf16x8*>(&Wt[col*Dd + swz*8]);
      acc[nf] = __builtin_amdgcn_mfma_f32_16x16x32_bf16(a, b, acc[nf], 0, 0, 0);
    }
  }

  if (which < 2){
    ushort_t* out = (which == 0) ? Qb : Kb;
    #pragma unroll
    for (int nf = 0; nf < 8; nf++){
      int col = nf*16 + lr;
      float bv_ = bia[col];
      #pragma unroll
      for (int r = 0; r < 4; r++){
        int grow = row0 + wave*16 + lg*4 + r;
        out[(size_t)grow*Dd + col] = f2bf((acc[nf][r] + bv_) * sc);
      }
    }
  } else {
    __syncthreads();
    #pragma unroll
    for (int nf = 0; nf < 8; nf++){
      int col = nf*16 + lr;
      float bv_ = bia[col];
      #pragma unroll
      for (int r = 0; r < 4; r++){
        int row_l = wave*16 + lg*4 + r;
        Brot[row_l*Dd + ((col + row_l) & 127)] = acc[nf][r] + bv_;
      }
    }
    __syncthreads();
    const int bb  = row0 >> 13;
    const int tq0 = row0 & (T - 1);
    const size_t vb = (size_t)bb * Dd * T;
    #pragma unroll 4
    for (int dd = 0; dd < 32; ++dd){
      int d = wave*32 + dd;
      float v = Brot[lane*Dd + ((d + lane) & 127)];
      VbT[vb + (size_t)d*T + tq0 + lane] = f2bf(v);
    }
  }
}

// ---------------------------------------------------------------------------
// Unified per-iteration attention step, FIXED-REPRESENTATIVE softmax:
// m_rep is frozen at the first tile's max; no in-loop rescale ever. The TRUE
// row max is tracked (fmax chain, zero per-tile shuffles) and reported
// separately (Pmt / used for mn in the update), which keeps the faithful
// ratio=new_d/d_old math exact -- partials are representative-invariant.
// Phase-B (is0) is kv-SPLIT by (1<<slog) to fill the chip at small iblk;
// slot = j*(1<<slog)+sp indexes the partial buffers (slots <= 8).
// P-halves exchange via 8 conditional shfl_xor (serves both halves at once).
// ---------------------------------------------------------------------------
__global__ __launch_bounds__(256)
void attn_step(const ushort_t* __restrict__ Qb, const ushort_t* __restrict__ Kb,
               const ushort_t* __restrict__ VbT,
               const ushort_t* __restrict__ VcTr, ushort_t* __restrict__ VcTw,
               float* __restrict__ VcF, float* __restrict__ m_st, float* __restrict__ d_st,
               float* __restrict__ Pacc, float* __restrict__ Pm, float* __restrict__ Pmt,
               float* __restrict__ Pd, int iblk, int slog)
{
  __shared__ __align__(16) char smem[65536];   // 2 x (K 16KB + V 16KB)

  const int tid  = threadIdx.x;
  const int wave = tid >> 6;
  const int lane = tid & 63;
  const int l31  = lane & 31;
  const int h    = lane >> 5;

  // XCD-aware bijective swizzle (gridDim.x is always a multiple of 8)
  const int nwg = gridDim.x;
  const int bi  = (blockIdx.x & 7) * (nwg >> 3) + (blockIdx.x >> 3);

  const int slots = (iblk + 1) << slog;
  const int g0 = slots << 6;            // 64 * slots
  const bool is0 = (bi < g0);

  int b, qt, qrow0, t0, slot, ktiles;
  const ushort_t *qsrc, *ksrc, *vhi;

  if (is0){
    slot = bi >> 6;
    int sp = slot & ((1 << slog) - 1);
    int j  = slot >> slog;
    int rem = bi & 63;
    b = rem >> 3; qt = rem & 7;
    qrow0 = b*T + iblk*N + qt*128;
    ktiles = TPC >> slog;
    t0 = j*N + sp*(ktiles*Nk);
    qsrc = Qb; ksrc = Kb;
    vhi = (j < iblk) ? VcTr : VbT;
  } else {
    int bi2 = bi - g0;
    int per = 8 * iblk;
    b = bi2 / per;
    int rem = bi2 - b*per;
    int j = rem >> 3; qt = rem & 7;      // j = jold
    qrow0 = b*T + j*N + qt*128;
    ktiles = TPC;
    t0 = iblk*N;
    qsrc = Kb; ksrc = Qb;
    vhi = VbT;
    slot = 0;
  }
  const int krow0base = b*T + t0;
  const size_t vbase = (size_t)b * Dd * T;
  const ushort_t* vhiB = vhi + vbase;

  // Per-thread staging source pointers (advance by constant stride per tile).
  const ushort_t* kp = ksrc + (size_t)(krow0base + (tid >> 4))*Dd
                            + (((tid & 15) ^ ((tid >> 4) & 7)) << 3);
  const ushort_t* vp = vhiB + (size_t)(tid >> 3)*T + t0
                            + (((tid & 7) ^ ((tid >> 3) & 7)) << 3);

  auto STAGE = [&](const ushort_t* kpp, const ushort_t* vpp, int bufi){
    char* dstb = smem + bufi*32768 + (wave << 10);
    char* dstv = dstb + 16384;
    #pragma unroll
    for (int it = 0; it < 4; ++it){
      gl16(kpp + it*16*Dd, dstb + it*4096);            // +16 rows per chunk
      gl16(vpp + (size_t)it*32*T, dstv + it*4096);     // +32 d-rows per chunk
    }
  };

  // Q fragments (B-operand): lane's q-row = qrow0 + wave*32 + l31,
  // k = ks*16 + h*8 + e  -> contiguous bf16x8 loads.
  bf16x8 qf[8];
  {
    const ushort_t* qp = qsrc + (size_t)(qrow0 + wave*32 + l31)*Dd + h*8;
    #pragma unroll
    for (int ks = 0; ks < 8; ++ks) qf[ks] = *reinterpret_cast<const bf16x8*>(qp + ks*16);
  }

  f32x16 o[4];
  #pragma unroll
  for (int db = 0; db < 4; ++db) o[db] = (f32x16)(0.0f);
  float m_rep  = 0.f;         // representative (frozen after tile 0)
  float tmax_h = -INFINITY;   // TRUE max, own half only (combined at end)
  float d_half = 0.f;         // rep-frame sum, own half only

  STAGE(kp, vp, 0);
  __syncthreads();             // vmcnt(0) + barrier: buf0 ready
  int cur = 0;

  for (int kt = 0; kt < ktiles; ++kt){
    if (kt + 1 < ktiles){
      kp += 64*Dd; vp += 64;
      STAGE(kp, vp, cur ^ 1);  // async: lands during compute below
    }
    const short* Kt  = (const short*)(smem + cur*32768);
    const short* Vt0 = (const short*)(smem + cur*32768 + 16384);

    // S^T = K . Q^T : C[kv][q], q = lane&31. For kt>0 the C-init is -m_rep,
    // so scores come out pre-biased (exp subtraction is free).
    const float cini = (kt == 0) ? 0.f : -m_rep;
    f32x16 c0 = (f32x16)(cini), c1 = (f32x16)(cini);
    __builtin_amdgcn_s_setprio(1);
    #pragma unroll
    for (int ks = 0; ks < 8; ++ks){
      int swz = (2*ks + h) ^ (l31 & 7);
      bf16x8 ka = *reinterpret_cast<const bf16x8*>(&Kt[l31*Dd + swz*8]);
      bf16x8 kb = *reinterpret_cast<const bf16x8*>(&Kt[(32 + l31)*Dd + swz*8]);
      c0 = __builtin_amdgcn_mfma_f32_32x32x16_bf16(ka, qf[ks], c0, 0, 0, 0);
      c1 = __builtin_amdgcn_mfma_f32_32x32x16_bf16(kb, qf[ks], c1, 0, 0, 0);
    }
    __builtin_amdgcn_s_setprio(0);

    // per-lane tile max over own 32 values (max3-fusable chain)
    float tm = fmaxf(c0[0], c0[1]);
    #pragma unroll
    for (int r = 2; r < 16; r += 2) tm = fmaxf(tm, fmaxf(c0[r], c0[r+1]));
    #pragma unroll
    for (int r = 0; r < 16; r += 2) tm = fmaxf(tm, fmaxf(c1[r], c1[r+1]));

    float ps = 0.f;
    if (kt == 0){
      tm = fmaxf(tm, __shfl_xor(tm, 32));   // combined -> wave-uniform per q
      m_rep  = tm;
      tmax_h = tm;
      #pragma unroll
      for (int r = 0; r < 16; ++r){ c0[r] = exp2v(c0[r] - m_rep); ps += c0[r]; }
      #pragma unroll
      for (int r = 0; r < 16; ++r){ c1[r] = exp2v(c1[r] - m_rep); ps += c1[r]; }
    } else {
      tmax_h = fmaxf(tmax_h, tm + m_rep);   // back to true frame
      #pragma unroll
      for (int r = 0; r < 16; ++r){ c0[r] = exp2v(c0[r]); ps += c0[r]; }
      #pragma unroll
      for (int r = 0; r < 16; ++r){ c1[r] = exp2v(c1[r]); ps += c1[r]; }
    }
    d_half += ps;

    // pack P to bf16 words (w[0..7] = c0 / kv 0..31, w[8..15] = c1 / kv 32..63)
    uint32 w[16];
    #pragma unroll
    for (int q = 0; q < 8; ++q){
      w[q]     = cvtpk(c0[2*q], c0[2*q+1]);
      w[8 + q] = cvtpk(c1[2*q], c1[2*q+1]);
    }

    // O += P @ V. Halves exchange folded in: one shfl serves both directions.
    __builtin_amdgcn_s_setprio(1);
    #pragma unroll
    for (int s = 0; s < 4; ++s){
      uint32 x0 = (uint32)__shfl_xor((int)(h ? w[4*s]   : w[4*s+2]), 32);
      uint32 x1 = (uint32)__shfl_xor((int)(h ? w[4*s+1] : w[4*s+3]), 32);
      union { uint32 u[4]; bf16x8 v; } af;
      af.u[0] = h ? x0 : w[4*s];
      af.u[1] = h ? x1 : w[4*s+1];
      af.u[2] = h ? w[4*s+2] : x0;
      af.u[3] = h ? w[4*s+3] : x1;
      #pragma unroll
      for (int db = 0; db < 4; ++db){
        int swz = (2*s + h) ^ (l31 & 7);
        bf16x8 bv = *reinterpret_cast<const bf16x8*>(&Vt0[(db*32 + l31)*Nk + swz*8]);
        o[db] = __builtin_amdgcn_mfma_f32_32x32x16_bf16(af.v, bv, o[db], 0, 0, 0);
      }
    }
    __builtin_amdgcn_s_setprio(0);

    __syncthreads();   // drains vmcnt (stage t+1) + all waves done with buf cur
    cur ^= 1;
  }

  // combine halves once
  const float tm_true = fmaxf(tmax_h, __shfl_xor(tmax_h, 32));
  const float d_tot   = d_half + __shfl_xor(d_half, 32);

  if (is0){
    // split-KV partial (rep frame): D rows = q (reg-mapped), cols = d
    const int prow_base = b*1024 + qt*128 + wave*32;
    float* pa = Pacc + (size_t)slot*8192*Dd;
    #pragma unroll
    for (int r = 0; r < 16; ++r){
      int qloc = (r & 3) + 8*(r >> 2) + 4*h;
      float* row = pa + (size_t)(prow_base + qloc)*Dd + l31;
      #pragma unroll
      for (int db = 0; db < 4; ++db) row[db*32] = o[db][r];
    }
    if (lane < 32){
      Pm [slot*8192 + prow_base + l31] = m_rep;
      Pmt[slot*8192 + prow_base + l31] = tm_true;
      Pd [slot*8192 + prow_base + l31] = d_tot;
    }
  } else {
    // faithful _update_state merge, in place on VcF (log2-domain, TRUE max)
    const int growo = qrow0 + wave*32 + l31;
    float mo   = m_st[growo];
    float dold = d_st[growo];
    float mn   = fmaxf(mo, tm_true);
    float se   = exp2v(m_rep - mn);          // rep-frame weight
    float nd   = dold * exp2v(mo - mn) + d_tot * se;
    float ratio = nd / dold;
    float accm  = se / nd;

    #pragma unroll
    for (int r = 0; r < 16; ++r){
      int rr = (r & 3) + 8*(r >> 2) + 4*h;
      float ratio_r = __shfl(ratio, rr);
      float accm_r  = __shfl(accm, rr);
      size_t base = (size_t)(qrow0 + wave*32 + rr)*Dd + l31;
      #pragma unroll
      for (int db = 0; db < 4; ++db){
        float v = ratio_r * VcF[base + db*32] + o[db][r] * accm_r;
        VcF[base + db*32] = v;
        o[db][r] = v;
      }
    }
    if (lane < 32){ m_st[growo] = mn; d_st[growo] = nd; }

    // bounce-transpose updated rows into VcT(write), bf16, per-wave 8KB
    ushort_t* brot = (ushort_t*)smem + wave*4096;   // 32 rows x 128, rotated
    const int tabs = (qrow0 - b*T) + wave*32 + l31;
    #pragma unroll
    for (int r = 0; r < 16; ++r){
      int rr = (r & 3) + 8*(r >> 2) + 4*h;
      #pragma unroll
      for (int db = 0; db < 4; ++db){
        int d = db*32 + l31;
        brot[rr*128 + ((d + rr) & 127)] = f2bf(o[db][r]);
      }
    }
    #pragma unroll 4
    for (int dd = 0; dd < 64; ++dd){
      int d = dd*2 + h;
      VcTw[vbase + (size_t)d*T + tabs] = brot[l31*128 + ((d + l31) & 127)];
    }
  }
}

// ---------------------------------------------------------------------------
// Merge split-KV partials -> block iblk rows of VcF, m_st, d_st, VcT(write).
// grid = 128 (b, qt64), 256 threads. M from TRUE maxima (Pmt); weights from
// the representatives (Pm) -- representative-invariant, exact.
// ---------------------------------------------------------------------------
__global__ __launch_bounds__(256)
void merge_kernel(const float* __restrict__ Pacc, const float* __restrict__ Pm,
                  const float* __restrict__ Pmt, const float* __restrict__ Pd,
                  float* __restrict__ VcF, float* __restrict__ m_st, float* __restrict__ d_st,
                  ushort_t* __restrict__ VcTw, int slots, int iblk)
{
  __shared__ float Brot[64*Dd];   // 32KB rotation layout
  const int bi = blockIdx.x;
  const int b = bi >> 4, qt = bi & 15;
  const int tid = threadIdx.x;
  const int lrow = tid >> 2, dq = tid & 3;
  const int prow = b*1024 + qt*64 + lrow;
  const int grow = b*T + iblk*N + qt*64 + lrow;

  float M = -INFINITY;
  for (int jj = 0; jj < slots; ++jj) M = fmaxf(M, Pmt[jj*8192 + prow]);

  float out[32];
  #pragma unroll
  for (int e = 0; e < 32; ++e) out[e] = 0.f;
  float D = 0.f;
  for (int jj = 0; jj < slots; ++jj){
    float wj = exp2v(Pm[jj*8192 + prow] - M);
    D += Pd[jj*8192 + prow] * wj;
    const float* pa = Pacc + ((size_t)jj*8192 + prow)*Dd + dq*32;
    #pragma unroll
    for (int e8 = 0; e8 < 8; ++e8){
      float4 v = *reinterpret_cast<const float4*>(pa + e8*4);
      out[e8*4+0] += v.x * wj;
      out[e8*4+1] += v.y * wj;
      out[e8*4+2] += v.z * wj;
      out[e8*4+3] += v.w * wj;
    }
  }
  float dinv = 1.f / D;
  #pragma unroll
  for (int e = 0; e < 32; ++e){
    int d = dq*32 + e;
    float v = out[e] * dinv;
    VcF[(size_t)grow*Dd + d] = v;
    Brot[lrow*Dd + ((d + lrow) & 127)] = v;
  }
  if (dq == 0){ m_st[grow] = M; d_st[grow] = D; }
  __syncthreads();

  const int wave = tid >> 6, lane = tid & 63;
  const int tq0 = iblk*N + qt*64;
  const size_t vb = (size_t)b * Dd * T;
  #pragma unroll 4
  for (int dd = 0; dd < 32; ++dd){
    int d = wave*32 + dd;
    float v = Brot[lane*Dd + ((d + lane) & 127)];
    VcTw[vb + (size_t)d*T + tq0 + lane] = f2bf(v);
  }
}

// ---------------------------------------------------------------------------
extern "C" void kernel_launch(void* const* d_in, const int* in_sizes, int n_in,
                              void* d_out, int out_size, void* d_ws, size_t ws_size,
                              hipStream_t stream)
{
  (void)in_sizes; (void)n_in; (void)out_size; (void)ws_size;

  const float* x  = (const float*)d_in[0];
  const float* Wq = (const float*)d_in[1];
  const float* bq = (const float*)d_in[2];
  const float* Wk = (const float*)d_in[3];
  const float* bk = (const float*)d_in[4];
  const float* Wv = (const float*)d_in[5];
  const float* bv = (const float*)d_in[6];

  float* VcF = (float*)d_out;          // fp32 master v_cache == output

  const size_t nt = (size_t)Bsz * T;   // 65536 rows
  char* p = (char*)d_ws;
  auto alloc = [&](size_t bytes) -> void* {
    void* r = (void*)p;
    p += (bytes + 255) & ~(size_t)255;
    return r;
  };
  ushort_t* Qb   = (ushort_t*)alloc(nt * Dd * 2);          // 16MB
  ushort_t* Kb   = (ushort_t*)alloc(nt * Dd * 2);          // 16MB
  ushort_t* VbT  = (ushort_t*)alloc(nt * Dd * 2);          // 16MB transposed raw V
  ushort_t* VcT[2];
  for (int c = 0; c < 2; ++c)
    VcT[c] = (ushort_t*)alloc(nt * Dd * 2);                // 2 x 16MB
  float* m_st = (float*)alloc(nt * 4);
  float* d_st = (float*)alloc(nt * 4);
  float* Pacc = (float*)alloc((size_t)NB * 8192 * Dd * 4); // 33.5MB
  float* Pm   = (float*)alloc((size_t)NB * 8192 * 4);
  float* Pmt  = (float*)alloc((size_t)NB * 8192 * 4);
  float* Pd   = (float*)alloc((size_t)NB * 8192 * 4);

  // 1/sqrt(128) * log2(e): scores computed directly in log2 domain
  const float scale = 0.08838834764831845f * 1.4426950408889634f;
  dim3 blk(256);

  proj_kernel<<<dim3((unsigned)(nt / 64), 3), blk, 0, stream>>>(
      x, Wq, bq, Wk, bk, Wv, bv, Qb, Kb, VbT, scale);

  // kv-split factors (log2) per iteration: fill ~512 co-resident blocks
  const int slogs[NB] = {3, 2, 1, 1, 0, 0, 0, 0};

  for (int i = 0; i < NB; ++i){
    const int wb = i & 1, rb = wb ^ 1;
    const int slog = slogs[i];
    const int slots = (i + 1) << slog;
    const int grid = 64 * slots + 64 * i;
    attn_step<<<grid, blk, 0, stream>>>(
        Qb, Kb, VbT, VcT[rb], VcT[wb],
        VcF, m_st, d_st, Pacc, Pm, Pmt, Pd, i, slog);
    merge_kernel<<<128, blk, 0, stream>>>(
        Pacc, Pm, Pmt, Pd, VcF, m_st, d_st, VcT[wb], slots, i);
  }
}